// Round 10
// baseline (2584.048 us; speedup 1.0000x reference)
//
#include <hip/hip_runtime.h>
#include <math.h>

#define TT 8
#define NN 4096
#define FF 128

// bf16 MFMA fragments as short8 (compile form verified on gfx950 in R6 PASS)
typedef short bf16x8 __attribute__((ext_vector_type(8)));
typedef float f32x4 __attribute__((ext_vector_type(4)));

__device__ inline ushort f2bf(float f) {              // RNE fp32 -> bf16 bits
  uint u = __float_as_uint(f);
  return (ushort)((u + 0x7fffu + ((u >> 16) & 1u)) >> 16);
}
__device__ inline float bf2f(ushort h) { return __uint_as_float(((uint)h) << 16); }

__device__ inline void split8(const float* v, uint4& H, uint4& L) {
  ushort h[8], l[8];
  #pragma unroll
  for (int j = 0; j < 8; ++j) {
    h[j] = f2bf(v[j]);
    l[j] = f2bf(v[j] - bf2f(h[j]));
  }
  H = make_uint4((uint)h[0] | ((uint)h[1] << 16), (uint)h[2] | ((uint)h[3] << 16),
                 (uint)h[4] | ((uint)h[5] << 16), (uint)h[6] | ((uint)h[7] << 16));
  L = make_uint4((uint)l[0] | ((uint)l[1] << 16), (uint)l[2] | ((uint)l[3] << 16),
                 (uint)l[4] | ((uint)l[5] << 16), (uint)l[6] | ((uint)l[7] << 16));
}

// ---------------------------------------------------------------------------
// p normalization: pn = p / ||p||
// ---------------------------------------------------------------------------
__global__ void norm_p_k(const float* __restrict__ p1, const float* __restrict__ p2,
                         float* __restrict__ pn1, float* __restrict__ pn2) {
  int b = blockIdx.x;
  int which = b >> 3, t = b & 7;
  const float* src = which ? p2 : p1;
  float* dst = which ? pn2 : pn1;
  int lane = threadIdx.x;
  float v0 = src[t*FF + lane];
  float v1 = src[t*FF + 64 + lane];
  float ss = v0*v0 + v1*v1;
  #pragma unroll
  for (int o = 32; o > 0; o >>= 1) ss += __shfl_xor(ss, o);
  float inv = 1.0f / sqrtf(ss);
  dst[t*FF + lane] = v0 * inv;
  dst[t*FF + 64 + lane] = v1 * inv;
}

// ---------------------------------------------------------------------------
// scores[t][n] = dot(src[t][n][:], pn[t][:])
// ---------------------------------------------------------------------------
__global__ __launch_bounds__(256)
void scores_k(const float* __restrict__ src, const float* __restrict__ pn,
              float* __restrict__ sc) {
  __shared__ float ps[FF];
  int t = blockIdx.y;
  int tid = threadIdx.x;
  if (tid < FF) ps[tid] = pn[t*FF + tid];
  __syncthreads();
  int row = blockIdx.x * 64 + (tid >> 2);
  int part = tid & 3;
  const float* rp = src + ((long)t*NN + row)*FF + part*32;
  float acc = 0.f;
  #pragma unroll
  for (int i = 0; i < 8; ++i) {
    float4 f = *reinterpret_cast<const float4*>(rp + i*4);
    const float* pp = ps + part*32 + i*4;
    acc += f.x*pp[0] + f.y*pp[1] + f.z*pp[2] + f.w*pp[3];
  }
  acc += __shfl_xor(acc, 1);
  acc += __shfl_xor(acc, 2);
  if (part == 0) sc[t*NN + row] = acc;
}

// ---------------------------------------------------------------------------
// Full bitonic sort (desc score, tie -> lower index), then
// z[t][r][c] = src[t][idx[c]][r] * tanh(vals[c]).  One block per t.
// ---------------------------------------------------------------------------
template<int K>
__global__ __launch_bounds__(1024)
void sortz_k(const float* __restrict__ sc, const float* __restrict__ src,
             float* __restrict__ z) {
  __shared__ float s[NN];
  __shared__ int  si[NN];
  __shared__ float tv[K];
  int t = blockIdx.x, tid = threadIdx.x;
  for (int i = tid; i < NN; i += 1024) { s[i] = sc[(long)t*NN + i]; si[i] = i; }
  __syncthreads();
  for (int k = 2; k <= NN; k <<= 1) {
    for (int j = k >> 1; j > 0; j >>= 1) {
      for (int i = tid; i < NN; i += 1024) {
        int l = i ^ j;
        if (l > i) {
          float a = s[i], b = s[l]; int ia = si[i], ib = si[l];
          bool dir = ((i & k) == 0);
          bool lp = (b > a) || (b == a && ib < ia);
          if (lp == dir) { s[i] = b; s[l] = a; si[i] = ib; si[l] = ia; }
        }
      }
      __syncthreads();
    }
  }
  if (tid < K) tv[tid] = tanhf(s[tid]);
  __syncthreads();
  for (int e = tid; e < FF*K; e += 1024) {
    int c = e >> 7, r = e & 127;
    z[((long)t*FF + r)*K + c] = src[((long)t*NN + si[c])*FF + r] * tv[c];
  }
}

// ---------------------------------------------------------------------------
// Fused GRU cells: ONE launch per layer, loops t=0..7 internally.
// Each block owns 16 columns for all 128 rows and the full t-chain.
// Textbook sync: load->sync->pass1->sync->pass2->sync->update->sync.
// ---------------------------------------------------------------------------
template<int C, bool WRITEALL>
__global__ __launch_bounds__(256)
void cells_k(const float* __restrict__ W, const float* __restrict__ U,
             const float* __restrict__ B, const float* __restrict__ z,
             const float* __restrict__ Q0, float* __restrict__ Qout) {
  __shared__ float zc[128][16], Qc[128][16], rq[128][16];
  int tid = threadIdx.x;
  int jj = tid & 15, ig = tid >> 4;
  int j0 = blockIdx.x * 16;
  #pragma unroll
  for (int p = 0; p < 8; ++p) {
    int e = p*256 + tid; int i = e >> 4, c = e & 15;
    Qc[i][c] = Q0[i*C + j0 + c];
  }
  __syncthreads();
  for (int t = 0; t < TT; ++t) {
    #pragma unroll
    for (int p = 0; p < 8; ++p) {
      int e = p*256 + tid; int i = e >> 4, c = e & 15;
      zc[i][c] = z[((long)t*128 + i)*C + j0 + c];
    }
    __syncthreads();
    float uu[8];
    #pragma unroll
    for (int rr = 0; rr < 8; ++rr) {
      int i = ig*8 + rr;
      float a0 = B[(0*128 + i)*C + j0 + jj];
      float a1 = B[(1*128 + i)*C + j0 + jj];
      const float* W0 = W + i*128;
      const float* W1 = W + 128*128 + i*128;
      const float* U0 = U + i*128;
      const float* U1 = U + 128*128 + i*128;
      #pragma unroll 4
      for (int k = 0; k < 128; ++k) {
        float zv = zc[k][jj], qv = Qc[k][jj];
        a0 += W0[k]*zv + U0[k]*qv;
        a1 += W1[k]*zv + U1[k]*qv;
      }
      float uv = 1.0f / (1.0f + expf(-a0));
      float rv = 1.0f / (1.0f + expf(-a1));
      uu[rr] = uv;
      rq[i][jj] = rv * Qc[i][jj];
    }
    __syncthreads();
    float qn[8];
    #pragma unroll
    for (int rr = 0; rr < 8; ++rr) {
      int i = ig*8 + rr;
      float ah = B[(2*128 + i)*C + j0 + jj];
      const float* W2 = W + 2*128*128 + i*128;
      const float* U2 = U + 2*128*128 + i*128;
      #pragma unroll 4
      for (int k = 0; k < 128; ++k)
        ah += W2[k]*zc[k][jj] + U2[k]*rq[k][jj];
      float hv = tanhf(ah);
      qn[rr] = (1.0f - uu[rr])*Qc[i][jj] + uu[rr]*hv;
    }
    __syncthreads();   // all pass-1/2 reads of Qc/zc done before overwrite
    #pragma unroll
    for (int rr = 0; rr < 8; ++rr) {
      int i = ig*8 + rr;
      Qc[i][jj] = qn[rr];
      if (WRITEALL || t == TT-1)
        Qout[((long)t*128 + i)*C + j0 + jj] = qn[rr];
    }
    __syncthreads();
  }
}

// ---------------------------------------------------------------------------
// X-mul + split-bf16 pack: Bp[t][k>>3][c][k&7] (hi, lo), C = 128 or 64.
// ---------------------------------------------------------------------------
template<int C>
__global__ __launch_bounds__(256)
void xmul_pack_k(const float* __restrict__ in, const float* __restrict__ Q,
                 ushort* __restrict__ Bph, ushort* __restrict__ Bpl,
                 long inST, long qST) {
  constexpr int RPT = C / 8;     // rows per thread: 16 (C=128) / 8 (C=64)
  __shared__ float Qs[64*C];
  __shared__ float ft[FF][36];
  int t = blockIdx.y;
  const float* inT = in + (long)t*inST;
  const float* QT  = Q  + (long)t*qST;
  int tid = threadIdx.x;
  int r0 = blockIdx.x * 32;
  for (int v = tid; v < 32*FF/4; v += 256) {
    int row = v >> 5, kq = v & 31;
    float4 f = *reinterpret_cast<const float4*>(inT + ((long)(r0+row))*FF + kq*4);
    ft[kq*4+0][row] = f.x; ft[kq*4+1][row] = f.y;
    ft[kq*4+2][row] = f.z; ft[kq*4+3][row] = f.w;
  }
  int c = tid & (C-1);
  int rh = tid / C;
  float acc[RPT];
  #pragma unroll
  for (int r = 0; r < RPT; ++r) acc[r] = 0.f;
  for (int kc = 0; kc < 2; ++kc) {
    __syncthreads();
    for (int v = tid*4; v < 64*C; v += 1024)
      *reinterpret_cast<float4*>(&Qs[v]) =
        *reinterpret_cast<const float4*>(QT + kc*64*C + v);
    __syncthreads();
    #pragma unroll 8
    for (int kl = 0; kl < 64; ++kl) {
      int k = kc*64 + kl;
      float qv = Qs[kl*C + c];
      const float* fr = &ft[k][rh*RPT];
      #pragma unroll
      for (int r4 = 0; r4 < RPT/4; ++r4) {
        float4 fv = *reinterpret_cast<const float4*>(fr + r4*4);
        acc[r4*4+0] += fv.x*qv; acc[r4*4+1] += fv.y*qv;
        acc[r4*4+2] += fv.z*qv; acc[r4*4+3] += fv.w*qv;
      }
    }
  }
  #pragma unroll
  for (int g = 0; g < RPT/8; ++g) {
    uint4 H, L;
    split8(&acc[g*8], H, L);
    long k0 = r0 + rh*RPT + g*8;
    long off = ((long)t*512*C + (k0 >> 3)*C + c)*8;
    *reinterpret_cast<uint4*>(&Bph[off]) = H;
    *reinterpret_cast<uint4*>(&Bpl[off]) = L;
  }
}

// ---------------------------------------------------------------------------
// Split-bf16 MFMA GEMM v3: H = act(A @ X), X pre-packed hi/lo.
// CANONICAL 2-barrier schedule (race-free; the R9 failure's fingerprint
// matched a stale-B race in v2's 1-barrier overlapped pipeline):
//   per 64-K interval: issue global loads (B chunks + A regs) ->
//   barrier#1 (WAR: prev compute done) -> ds_write B -> barrier#2 ->
//   split8(A) + MFMA. Single-buffered B in LDS (32 KB).
// Global loads are issued BEFORE barrier#1 so HBM latency overlaps the wait.
// 3-product split AhiBhi + AloBhi + AhiBlo (numerics verified R6).
// ---------------------------------------------------------------------------
template<int BN, int BM, bool RELU>
__global__ __launch_bounds__((BM/16)*64, 2)
void gemm_mfma_k(const float* __restrict__ A, const ushort* __restrict__ Bph,
                 const ushort* __restrict__ Bpl, float* __restrict__ H, int nt) {
  constexpr int TH = (BM/16)*64;     // threads
  constexpr int NF = BN/16;          // n-fragments
  constexpr int BI = BN*64;          // ushorts per interval per (hi|lo)
  constexpr int NCH = BI/(TH*8);     // staging chunks per thread (=4)
  __shared__ ushort BhL[BI];
  __shared__ ushort BlL[BI];
  int bid = blockIdx.x;
  int t  = (nt == 8) ? (bid & 7) : 0;        // one t per XCD (L2 residency)
  int mb = (nt == 8) ? (bid >> 3) : bid;
  const float*  At  = A   + (size_t)t*NN*NN + (size_t)mb*BM*NN;
  const ushort* BhT = Bph + (size_t)t*512*BN*8;
  const ushort* BlT = Bpl + (size_t)t*512*BN*8;
  float* Ht = H + (size_t)t*NN*BN + (size_t)mb*BM*BN;

  int tid = threadIdx.x;
  int wv = tid >> 6, lane = tid & 63;
  int lg = lane >> 4, lr = lane & 15;

  const float* aB = At + (size_t)(wv*16 + lr)*NN + lg*8;

  f32x4 acc[NF];
  #pragma unroll
  for (int n = 0; n < NF; ++n) acc[n] = (f32x4){0.f, 0.f, 0.f, 0.f};

  for (int iv = 0; iv < 64; ++iv) {
    // issue all global loads for this interval (in flight across barrier#1)
    uint4 bb[NCH], cc[NCH];
    const ushort* bhg = BhT + (size_t)iv*BI + tid*8;
    const ushort* blg = BlT + (size_t)iv*BI + tid*8;
    #pragma unroll
    for (int ch = 0; ch < NCH; ++ch) {
      bb[ch] = *reinterpret_cast<const uint4*>(bhg + ch*TH*8);
      cc[ch] = *reinterpret_cast<const uint4*>(blg + ch*TH*8);
    }
    const float* ap = aB + (size_t)iv*64;
    float4 a0 = *reinterpret_cast<const float4*>(ap);
    float4 a1 = *reinterpret_cast<const float4*>(ap + 4);
    float4 a2 = *reinterpret_cast<const float4*>(ap + 32);
    float4 a3 = *reinterpret_cast<const float4*>(ap + 36);

    __syncthreads();               // WAR: previous interval's reads complete
    #pragma unroll
    for (int ch = 0; ch < NCH; ++ch) {
      *reinterpret_cast<uint4*>(&BhL[tid*8 + ch*TH*8]) = bb[ch];
      *reinterpret_cast<uint4*>(&BlL[tid*8 + ch*TH*8]) = cc[ch];
    }
    __syncthreads();               // stores visible to all waves

    auto dohalf = [&](float4 x0, float4 x1, int ss) {
      float v[8] = {x0.x, x0.y, x0.z, x0.w, x1.x, x1.y, x1.z, x1.w};
      uint4 Hh, Ll; split8(v, Hh, Ll);
      bf16x8 ah = *reinterpret_cast<bf16x8*>(&Hh);
      bf16x8 al = *reinterpret_cast<bf16x8*>(&Ll);
      int base = (ss*4 + lg)*BN*8 + lr*8;
      #pragma unroll
      for (int n = 0; n < NF; ++n) {
        bf16x8 bh = *reinterpret_cast<const bf16x8*>(&BhL[base + n*128]);
        bf16x8 bl = *reinterpret_cast<const bf16x8*>(&BlL[base + n*128]);
        acc[n] = __builtin_amdgcn_mfma_f32_16x16x32_bf16(ah, bh, acc[n], 0, 0, 0);
        acc[n] = __builtin_amdgcn_mfma_f32_16x16x32_bf16(al, bh, acc[n], 0, 0, 0);
        acc[n] = __builtin_amdgcn_mfma_f32_16x16x32_bf16(ah, bl, acc[n], 0, 0, 0);
      }
    };
    dohalf(a0, a1, 0);
    dohalf(a2, a3, 1);
  }

  // D[row][col]: col = lane&15, row = (lane>>4)*4 + v  [HW-verified R6]
  #pragma unroll
  for (int n = 0; n < NF; ++n)
    #pragma unroll
    for (int v = 0; v < 4; ++v) {
      float x = acc[n][v];
      Ht[(size_t)(16*wv + lg*4 + v)*BN + 16*n + lr] = RELU ? fmaxf(x, 0.f) : x;
    }
}

// ---------------------------------------------------------------------------
extern "C" void kernel_launch(void* const* d_in, const int* in_sizes, int n_in,
                              void* d_out, int out_size, void* d_ws, size_t ws_size,
                              hipStream_t stream) {
  (void)in_sizes; (void)n_in; (void)out_size; (void)ws_size;
  const float* adj   = (const float*)d_in[0];
  const float* feats = (const float*)d_in[1];
  const float* p1    = (const float*)d_in[2];
  const float* p2    = (const float*)d_in[3];
  const float* W1    = (const float*)d_in[4];
  const float* U1    = (const float*)d_in[5];
  const float* B1    = (const float*)d_in[6];
  const float* iW1   = (const float*)d_in[7];
  const float* W2    = (const float*)d_in[8];
  const float* U2    = (const float*)d_in[9];
  const float* B2    = (const float*)d_in[10];
  const float* iW2   = (const float*)d_in[11];
  float* out = (float*)d_out;
  float* ws  = (float*)d_ws;

  const long NF_ = (long)NN*FF;                // 524288
  ushort* Bph = (ushort*)ws;                   // 4,194,304 ushorts
  ushort* Bpl = (ushort*)(ws + 2097152);       // 4,194,304 ushorts
  float* h1  = ws + 4194304;                   // 8*NF_
  float* sc  = ws + 8388608;                   // 8*4096
  float* pn1 = ws + 8421376;                   // 1024
  float* pn2 = ws + 8422400;                   // 1024
  float* z1  = ws + 8423424;                   // 8*128*128
  float* z2  = ws + 8554496;                   // 8*128*64
  float* Q1  = ws + 8620032;                   // 8*128*128
  float* Q2  = ws + 8751104;                   // 8*128*64
  ushort* Yh = (ushort*)(ws + 8816640);        // 262144 ushorts
  ushort* Yl = Yh + 262144;                    // 262144 ushorts
  // total 9,078,784 floats = 36.3 MB of d_ws

  norm_p_k<<<16, 64, 0, stream>>>(p1, p2, pn1, pn2);

  // ---- layer 1 ----
  scores_k<<<dim3(64,8), 256, 0, stream>>>(feats, pn1, sc);
  sortz_k<128><<<8, 1024, 0, stream>>>(sc, feats, z1);
  cells_k<128, true><<<8, 256, 0, stream>>>(W1, U1, B1, z1, iW1, Q1);
  xmul_pack_k<128><<<dim3(128,8), 256, 0, stream>>>(feats, Q1, Bph, Bpl,
                                                    NF_, 128*128);
  gemm_mfma_k<128,64,true><<<512, 256, 0, stream>>>(adj, Bph, Bpl, h1, 8);

  // ---- layer 2 (emb only needed at t=7) ----
  scores_k<<<dim3(64,8), 256, 0, stream>>>(h1, pn2, sc);
  sortz_k<64><<<8, 1024, 0, stream>>>(sc, h1, z2);
  cells_k<64, false><<<4, 256, 0, stream>>>(W2, U2, B2, z2, iW2, Q2);
  xmul_pack_k<64><<<dim3(128,1), 256, 0, stream>>>(h1 + 7*NF_,
                                                   Q2 + (long)7*128*64,
                                                   Yh, Yl, 0, 0);
  gemm_mfma_k<64,32,false><<<128, 128, 0, stream>>>(adj + (size_t)7*NN*NN,
                                                    Yh, Yl, out, 1);
}